// Round 4
// baseline (3120.159 us; speedup 1.0000x reference)
//
#include <hip/hip_runtime.h>
#include <math.h>

#define DTOK 1222
#define NBOU 80
#define MM   160
#define FFD  2048
#define OQKV 3666

typedef __attribute__((ext_vector_type(8))) short short8;
typedef __attribute__((ext_vector_type(4))) float f32x4;

// ---------- bf16 helpers ----------
__device__ __forceinline__ unsigned short f2bf(float x) {
  unsigned int u = __float_as_uint(x);
  unsigned int r = (u + 0x7FFFu + ((u >> 16) & 1u)) >> 16;
  return (unsigned short)r;
}
__device__ __forceinline__ float bf2f(unsigned short h) {
  return __uint_as_float((unsigned int)h << 16);
}

// ---------- reduction helpers (block = 256 threads = 4 waves) ----------
__device__ __forceinline__ float wave_red_sum(float v) {
#pragma unroll
  for (int off = 32; off; off >>= 1) v += __shfl_xor(v, off, 64);
  return v;
}

__device__ __forceinline__ float block_red_sum(float v, float* rb, int tid) {
  v = wave_red_sum(v);
  __syncthreads();
  if ((tid & 63) == 0) rb[tid >> 6] = v;
  __syncthreads();
  return rb[0] + rb[1] + rb[2] + rb[3];
}

// ---------- setup: pool L0 (NCHW) -> L1 (NHWC) ----------
__global__ __launch_bounds__(256) void k_pool0(const float* __restrict__ f,
                                               float* __restrict__ L1out) {
  int xc = blockIdx.x & 3, cc = blockIdx.x >> 2;
  int y1 = blockIdx.y, b = blockIdx.z;
  int tid = threadIdx.x;
  __shared__ __align__(16) float tile[64][116];
  int c0 = cc * 64, x0 = xc * 56;
  const float* fb = f + (size_t)b * 1024 * 50176;
#pragma unroll
  for (int i = 0; i < 7; ++i) {
    int u = tid + 256 * i;
    int q = u % 14;
    int seg = u / 14;
    int c = seg >> 1, r = seg & 1;
    const float* src = fb + ((size_t)(c0 + c) * 224 + (2 * y1 + r)) * 224 + x0 + q * 4;
    float4 v = *(const float4*)src;
    *(float4*)&tile[c][r * 56 + q * 4] = v;
  }
  __syncthreads();
#pragma unroll
  for (int i = 0; i < 7; ++i) {
    int u = tid + 256 * i;
    int xo = u >> 6;
    int c = u & 63;
    float v = 0.25f * (tile[c][2 * xo] + tile[c][2 * xo + 1] +
                       tile[c][56 + 2 * xo] + tile[c][56 + 2 * xo + 1]);
    L1out[(((size_t)b * 112 + y1) * 112 + (x0 >> 1) + xo) * 1024 + c0 + c] = v;
  }
}

// ---------- setup: pool NHWC -> NHWC (2x2 mean) ----------
__global__ __launch_bounds__(256) void k_pool_nhwc(const float* __restrict__ in,
                                                   float* __restrict__ out, int Ho) {
  int x = blockIdx.x, y = blockIdx.y, b = blockIdx.z;
  int c = threadIdx.x * 4;
  int Hi = Ho * 2;
  const float* p00 = in + (((size_t)(b * Hi + 2 * y) * Hi) + 2 * x) * 1024 + c;
  const float* p01 = p00 + 1024;
  const float* p10 = p00 + (size_t)Hi * 1024;
  const float* p11 = p10 + 1024;
  float4 a = *(const float4*)p00, bv = *(const float4*)p01;
  float4 cv = *(const float4*)p10, dv = *(const float4*)p11;
  float4 r;
  r.x = 0.25f * (a.x + bv.x + cv.x + dv.x);
  r.y = 0.25f * (a.y + bv.y + cv.y + dv.y);
  r.z = 0.25f * (a.z + bv.z + cv.z + dv.z);
  r.w = 0.25f * (a.w + bv.w + cv.w + dv.w);
  *(float4*)(out + (((size_t)(b * Ho + y) * Ho) + x) * 1024 + c) = r;
}

// ---------- setup: positional encoding + boundary init ----------
__global__ __launch_bounds__(256) void k_pe(float* __restrict__ pe, int* __restrict__ bnd,
                                            const int* __restrict__ pb) {
  int n = blockIdx.x, tid = threadIdx.x;
  for (int d = tid; d < DTOK; d += 256) {
    int i = d >> 1;
    double e = exp((double)(2 * i) * (-log(10000.0) / (double)DTOK));
    double ang = (double)n * e;
    pe[n * DTOK + d] = (float)((d & 1) ? cos(ang) : sin(ang));
  }
  if (n == 0) {
    for (int t = tid; t < 2 * NBOU * 2; t += 256) bnd[t] = pb[t];
  }
}

// ---------- per-iteration: gather + dots + tokens + LN + pe ----------
__global__ __launch_bounds__(256) void k_tok(const float* __restrict__ f,
                                             const float* __restrict__ L1,
                                             const float* __restrict__ L2,
                                             const float* __restrict__ L3,
                                             const int* __restrict__ bnd,
                                             const float* __restrict__ g,
                                             const float* __restrict__ bb,
                                             const float* __restrict__ pe,
                                             float* __restrict__ tok_out) {
  int blk = blockIdx.x;
  int b = blk / NBOU, n = blk % NBOU;
  int tid = threadIdx.x, wave = tid >> 6, lane = tid & 63;
  __shared__ __align__(16) float token[1224];
  __shared__ float red[4][52];
  __shared__ float rbuf[8];
  int bd0 = bnd[blk * 2 + 0], bd1 = bnd[blk * 2 + 1];

  int oh = lane / 7 - 3, ow = lane % 7 - 3;
  int py = bd0 + oh, px = bd1 + ow;
  bool valid = (lane < 49) && (py >= 0) && (py < 224) && (px >= 0) && (px < 224);
  const float* fb = f + (size_t)b * 1024 * 50176;
  long sp = (long)py * 224 + px;
  float acc0 = 0.f;
  int c0 = wave * 256;
#pragma unroll 8
  for (int c = 0; c < 256; ++c) {
    int ch = c0 + c;
    float v = valid ? fb[(size_t)ch * 50176 + sp] : 0.f;
    float qc = __shfl(v, 24, 64);
    acc0 += qc * v;
    if (lane == 24) token[ch] = v;
  }
  if (lane < 49) red[wave][lane] = acc0;
  __syncthreads();
  if (tid < 49) token[1024 + tid] = red[0][tid] + red[1][tid] + red[2][tid] + red[3][tid];
  if (tid == 0) { token[1220] = (float)bd0; token[1221] = (float)bd1; }
  __syncthreads();

#pragma unroll
  for (int s = 1; s <= 3; ++s) {
    const float* base = (s == 1) ? L1 : (s == 2) ? L2 : L3;
    int Hs = 224 >> s;
    int by = bd0 >> s, bx = bd1 >> s;
    const float* bp = base + (size_t)b * Hs * Hs * 1024;
    for (int o = wave; o < 49; o += 4) {
      int yy = by + o / 7 - 3, xx = bx + o % 7 - 3;
      float a = 0.f;
      if (yy >= 0 && yy < Hs && xx >= 0 && xx < Hs) {
        const float* kp = bp + ((size_t)yy * Hs + xx) * 1024;
#pragma unroll
        for (int j = 0; j < 4; ++j) {
          int c = (lane + 64 * j) * 4;
          float4 kv = *(const float4*)(kp + c);
          float4 qv = *(const float4*)(token + c);
          a += kv.x * qv.x + kv.y * qv.y + kv.z * qv.z + kv.w * qv.w;
        }
      }
      a = wave_red_sum(a);
      if (lane == 0) token[1024 + s * 49 + o] = a;
    }
  }
  __syncthreads();

  float ls = 0.f;
  for (int d = tid; d < DTOK; d += 256) ls += token[d];
  float mean = block_red_sum(ls, rbuf, tid) * (1.0f / DTOK);
  float lq = 0.f;
  for (int d = tid; d < DTOK; d += 256) { float t = token[d] - mean; lq += t * t; }
  float var = block_red_sum(lq, rbuf, tid) * (1.0f / DTOK);
  float rstd = rsqrtf(var + 1e-5f);
  for (int d = tid; d < DTOK; d += 256) {
    float o = (token[d] - mean) * rstd * g[d] + bb[d] + pe[n * DTOK + d];
    tok_out[(size_t)blk * DTOK + d] = o;
  }
}

// ---------- convert fp32 [R][K] -> 3-split bf16 fragment-linear [RT][T][3][4][64][8] ----------
__global__ __launch_bounds__(256) void k_conv(const float* __restrict__ X,
                                              short* __restrict__ F,
                                              int R, int K, int T) {
  int b = blockIdx.x;
  int rt = b / T, t = b % T;
  int tid = threadIdx.x, mf = tid >> 6, lane = tid & 63;
  int row = rt * 64 + mf * 16 + (lane & 15);
  int k0 = t * 32 + (lane >> 4) * 8;
  float a[8];
#pragma unroll
  for (int j = 0; j < 8; ++j) {
    int k = k0 + j;
    a[j] = (row < R && k < K) ? X[(size_t)row * K + k] : 0.f;
  }
  short8 h, l, q;
#pragma unroll
  for (int j = 0; j < 8; ++j) {
    float x = a[j];
    unsigned short hb = f2bf(x);
    float r1 = x - bf2f(hb);
    unsigned short lb = f2bf(r1);
    float r2 = r1 - bf2f(lb);
    unsigned short qb = f2bf(r2);
    h[j] = (short)hb; l[j] = (short)lb; q[j] = (short)qb;
  }
  size_t base = (size_t)b * 6144 + mf * 512 + (size_t)lane * 8;
  *(short8*)(F + base) = h;
  *(short8*)(F + base + 2048) = l;
  *(short8*)(F + base + 4096) = q;
}

// ---------- MFMA GEMM (split-bf16, 6 products ~ fp32): out[160,O] = A@W^T +bias (+relu)(+res) ----------
// grid (NT, 3). 64x64 tile, 4 waves of 32x32. Frag-linear inputs from k_conv.
__global__ __launch_bounds__(256) void k_mfma(const short* __restrict__ Af,
                                              const short* __restrict__ Bf,
                                              const float* __restrict__ bias,
                                              const float* __restrict__ res,
                                              float* __restrict__ out,
                                              int T, int O, int relu) {
  int nt = blockIdx.x, mt = blockIdx.y;
  int tid = threadIdx.x, w = tid >> 6, lane = tid & 63;
  int wr = w >> 1, wc = w & 1;
  __shared__ __align__(16) short Al[6144];
  __shared__ __align__(16) short Bl[6144];

  f32x4 acc[2][2];
#pragma unroll
  for (int mi = 0; mi < 2; ++mi)
#pragma unroll
    for (int ni = 0; ni < 2; ++ni) acc[mi][ni] = (f32x4){0.f, 0.f, 0.f, 0.f};

  short8 ra[3], rb[3], ra2[3] = {}, rb2[3] = {};
  {
    const short8* gA = (const short8*)(Af + (size_t)mt * T * 6144);
    const short8* gB = (const short8*)(Bf + (size_t)nt * T * 6144);
#pragma unroll
    for (int j = 0; j < 3; ++j) { ra[j] = gA[j * 256 + tid]; rb[j] = gB[j * 256 + tid]; }
  }

  for (int t = 0; t < T; ++t) {
    __syncthreads();
#pragma unroll
    for (int j = 0; j < 3; ++j) {
      ((short8*)Al)[j * 256 + tid] = ra[j];
      ((short8*)Bl)[j * 256 + tid] = rb[j];
    }
    if (t + 1 < T) {
      const short8* gA = (const short8*)(Af + ((size_t)mt * T + t + 1) * 6144);
      const short8* gB = (const short8*)(Bf + ((size_t)nt * T + t + 1) * 6144);
#pragma unroll
      for (int j = 0; j < 3; ++j) { ra2[j] = gA[j * 256 + tid]; rb2[j] = gB[j * 256 + tid]; }
    }
    __syncthreads();

    const short8* Av = (const short8*)Al;
    const short8* Bv = (const short8*)Bl;
    short8 af[3][2], bv[3][2];
#pragma unroll
    for (int s = 0; s < 3; ++s) {
      af[s][0] = Av[(s * 4 + wr * 2 + 0) * 64 + lane];
      af[s][1] = Av[(s * 4 + wr * 2 + 1) * 64 + lane];
      bv[s][0] = Bv[(s * 4 + wc * 2 + 0) * 64 + lane];
      bv[s][1] = Bv[(s * 4 + wc * 2 + 1) * 64 + lane];
    }
#pragma unroll
    for (int mi = 0; mi < 2; ++mi)
#pragma unroll
      for (int ni = 0; ni < 2; ++ni) {
        f32x4 a = acc[mi][ni];
        a = __builtin_amdgcn_mfma_f32_16x16x32_bf16(af[0][mi], bv[0][ni], a, 0, 0, 0); // hh
        a = __builtin_amdgcn_mfma_f32_16x16x32_bf16(af[0][mi], bv[1][ni], a, 0, 0, 0); // hl
        a = __builtin_amdgcn_mfma_f32_16x16x32_bf16(af[1][mi], bv[0][ni], a, 0, 0, 0); // lh
        a = __builtin_amdgcn_mfma_f32_16x16x32_bf16(af[0][mi], bv[2][ni], a, 0, 0, 0); // h3
        a = __builtin_amdgcn_mfma_f32_16x16x32_bf16(af[2][mi], bv[0][ni], a, 0, 0, 0); // 3h
        a = __builtin_amdgcn_mfma_f32_16x16x32_bf16(af[1][mi], bv[1][ni], a, 0, 0, 0); // ll
        acc[mi][ni] = a;
      }
#pragma unroll
    for (int j = 0; j < 3; ++j) { ra[j] = ra2[j]; rb[j] = rb2[j]; }
  }

  int r0 = mt * 64 + wr * 32;
  int c0 = nt * 64 + wc * 32;
#pragma unroll
  for (int mi = 0; mi < 2; ++mi)
#pragma unroll
    for (int ni = 0; ni < 2; ++ni) {
      int c = c0 + ni * 16 + (lane & 15);
      if (c >= O) continue;
#pragma unroll
      for (int reg = 0; reg < 4; ++reg) {
        int r = r0 + mi * 16 + (lane >> 4) * 4 + reg;
        if (r >= MM) continue;
        float v = acc[mi][ni][reg] + bias[c];
        if (relu) v = fmaxf(v, 0.f);
        if (res) v += res[(size_t)r * O + c];
        out[(size_t)r * O + c] = v;
      }
    }
}

// ---------- attention (per (b,n) row) ----------
__global__ __launch_bounds__(256) void k_attn(const float* __restrict__ qkv,
                                              float* __restrict__ attn_out) {
  int blk = blockIdx.x;
  int b = blk / NBOU;
  int tid = threadIdx.x, wave = tid >> 6, lane = tid & 63;
  __shared__ float p[80];
  float qr[20];
  const float* qrow = qkv + (size_t)blk * OQKV;
#pragma unroll
  for (int j = 0; j < 20; ++j) {
    int d = lane + 64 * j;
    qr[j] = (d < DTOK) ? qrow[d] : 0.f;
  }
  for (int m2 = wave; m2 < 80; m2 += 4) {
    const float* krow = qkv + (size_t)(b * NBOU + m2) * OQKV + DTOK;
    float a = 0.f;
#pragma unroll
    for (int j = 0; j < 20; ++j) {
      int d = lane + 64 * j;
      if (d < DTOK) a += qr[j] * krow[d];
    }
    a = wave_red_sum(a);
    if (lane == 0) p[m2] = a * (1.0f / 34.957116f);
  }
  __syncthreads();
  if (wave == 0) {
    float x0 = p[lane];
    float x1 = (lane < 16) ? p[64 + lane] : -INFINITY;
    float mx = fmaxf(x0, x1);
#pragma unroll
    for (int off = 32; off; off >>= 1) mx = fmaxf(mx, __shfl_xor(mx, off, 64));
    float e0 = expf(x0 - mx);
    float e1 = (lane < 16) ? expf(x1 - mx) : 0.f;
    float ssum = wave_red_sum(e0 + e1);
    p[lane] = e0 / ssum;
    if (lane < 16) p[64 + lane] = e1 / ssum;
  }
  __syncthreads();
  float acc[5] = {0, 0, 0, 0, 0};
  for (int m2 = 0; m2 < 80; ++m2) {
    float pm = p[m2];
    const float* vrow = qkv + (size_t)(b * NBOU + m2) * OQKV + 2 * DTOK;
#pragma unroll
    for (int i = 0; i < 5; ++i) {
      int d = tid + 256 * i;
      if (d < DTOK) acc[i] += pm * vrow[d];
    }
  }
#pragma unroll
  for (int i = 0; i < 5; ++i) {
    int d = tid + 256 * i;
    if (d < DTOK) attn_out[(size_t)blk * DTOK + d] = acc[i];
  }
}

// ---------- LayerNorm ----------
__global__ __launch_bounds__(256) void k_ln(const float* __restrict__ xin,
                                            const float* __restrict__ g,
                                            const float* __restrict__ bb,
                                            float* __restrict__ xout) {
  int m = blockIdx.x, tid = threadIdx.x;
  __shared__ float row[DTOK];
  __shared__ float rb[8];
  const float* xr = xin + (size_t)m * DTOK;
  float ls = 0.f;
  for (int d = tid; d < DTOK; d += 256) { float v = xr[d]; row[d] = v; ls += v; }
  float mean = block_red_sum(ls, rb, tid) * (1.0f / DTOK);
  float lq = 0.f;
  for (int d = tid; d < DTOK; d += 256) { float t = row[d] - mean; lq += t * t; }
  float var = block_red_sum(lq, rb, tid) * (1.0f / DTOK);
  float rstd = rsqrtf(var + 1e-5f);
  for (int d = tid; d < DTOK; d += 256)
    xout[(size_t)m * DTOK + d] = (row[d] - mean) * rstd * g[d] + bb[d];
}

// ---------- fc head (only outputs 0,1) + boundary update ----------
__global__ __launch_bounds__(256) void k_fc(const float* __restrict__ x2,
                                            const float* __restrict__ fcw,
                                            const float* __restrict__ fcb,
                                            int* __restrict__ bnd,
                                            int* __restrict__ outp) {
  int blk = blockIdx.x;
  int n = blk % NBOU;
  int tid = threadIdx.x;
  __shared__ float rb[8];
  const float* xr = x2 + (size_t)blk * DTOK;
  const float* w0 = fcw + (size_t)n * 1026 * DTOK;
  const float* w1 = w0 + DTOK;
  float s0 = 0.f, s1 = 0.f;
  for (int d = tid; d < DTOK; d += 256) {
    float x = xr[d];
    s0 += x * w0[d];
    s1 += x * w1[d];
  }
  s0 = block_red_sum(s0, rb, tid);
  s1 = block_red_sum(s1, rb, tid);
  if (tid == 0) {
    float o0 = s0 + fcb[n * 1026 + 0];
    float o1 = s1 + fcb[n * 1026 + 1];
    int b0 = bnd[blk * 2 + 0], b1 = bnd[blk * 2 + 1];
    int nb0 = b0 + (int)truncf(o0);
    int nb1 = b1 + (int)truncf(o1);
    nb0 = nb0 < 0 ? 0 : (nb0 > 223 ? 223 : nb0);
    nb1 = nb1 < 0 ? 0 : (nb1 > 223 ? 223 : nb1);
    bnd[blk * 2 + 0] = nb0;
    bnd[blk * 2 + 1] = nb1;
    outp[blk * 2 + 0] = nb0;
    outp[blk * 2 + 1] = nb1;
  }
}

extern "C" void kernel_launch(void* const* d_in, const int* in_sizes, int n_in,
                              void* d_out, int out_size, void* d_ws, size_t ws_size,
                              hipStream_t stream) {
  const float* f   = (const float*)d_in[0];
  const int*   pb  = (const int*)d_in[1];
  const float* lng = (const float*)d_in[2];
  const float* lnb = (const float*)d_in[3];
  const float* ipw = (const float*)d_in[4];
  const float* ipb = (const float*)d_in[5];
  const float* opw = (const float*)d_in[6];
  const float* opb = (const float*)d_in[7];
  const float* l1w = (const float*)d_in[8];
  const float* l1b = (const float*)d_in[9];
  const float* l2w = (const float*)d_in[10];
  const float* l2b = (const float*)d_in[11];
  const float* n1g = (const float*)d_in[12];
  const float* n1b = (const float*)d_in[13];
  const float* n2g = (const float*)d_in[14];
  const float* n2b = (const float*)d_in[15];
  const float* fcw = (const float*)d_in[16];
  const float* fcb = (const float*)d_in[17];
  int* outp = (int*)d_out;

  const int T1 = 39;   // ceil(1222/32)
  const int T2 = 64;   // 2048/32
  const int NT_IP = 58, NT_OP = 20, NT_L1 = 32, NT_L2 = 20;

  char* wsb = (char*)d_ws;
  auto alloc = [&](size_t bytes) -> char* {
    char* p = wsb;
    wsb += (bytes + 255) & ~(size_t)255;
    return p;
  };
  float* L1   = (float*)alloc((size_t)2 * 112 * 112 * 1024 * 4);
  float* L2   = (float*)alloc((size_t)2 * 56 * 56 * 1024 * 4);
  float* L3   = (float*)alloc((size_t)2 * 28 * 28 * 1024 * 4);
  float* pe   = (float*)alloc((size_t)NBOU * DTOK * 4);
  int*   bnd  = (int*)alloc(320 * 4);
  float* tokens = (float*)alloc((size_t)MM * DTOK * 4);
  float* qkvb   = (float*)alloc((size_t)MM * OQKV * 4);
  float* attnb  = (float*)alloc((size_t)MM * DTOK * 4);
  float* x1pre  = (float*)alloc((size_t)MM * DTOK * 4);
  float* x1     = (float*)alloc((size_t)MM * DTOK * 4);
  float* hb     = (float*)alloc((size_t)MM * FFD * 4);
  float* x2pre  = (float*)alloc((size_t)MM * DTOK * 4);
  float* x2     = (float*)alloc((size_t)MM * DTOK * 4);
  short* ipWf = (short*)alloc((size_t)NT_IP * T1 * 6144 * 2);
  short* opWf = (short*)alloc((size_t)NT_OP * T1 * 6144 * 2);
  short* l1Wf = (short*)alloc((size_t)NT_L1 * T1 * 6144 * 2);
  short* l2Wf = (short*)alloc((size_t)NT_L2 * T2 * 6144 * 2);
  short* Afrag = (short*)alloc((size_t)3 * T2 * 6144 * 2);

  k_pool0<<<dim3(64, 112, 2), 256, 0, stream>>>(f, L1);
  k_pool_nhwc<<<dim3(56, 56, 2), 256, 0, stream>>>(L1, L2, 56);
  k_pool_nhwc<<<dim3(28, 28, 2), 256, 0, stream>>>(L2, L3, 28);
  k_pe<<<NBOU, 256, 0, stream>>>(pe, bnd, pb);

  // one-time weight conversion to frag-linear split-bf16
  k_conv<<<NT_IP * T1, 256, 0, stream>>>(ipw, ipWf, OQKV, DTOK, T1);
  k_conv<<<NT_OP * T1, 256, 0, stream>>>(opw, opWf, DTOK, DTOK, T1);
  k_conv<<<NT_L1 * T1, 256, 0, stream>>>(l1w, l1Wf, FFD, DTOK, T1);
  k_conv<<<NT_L2 * T2, 256, 0, stream>>>(l2w, l2Wf, DTOK, FFD, T2);

  for (int it = 0; it < 6; ++it) {
    k_tok<<<160, 256, 0, stream>>>(f, L1, L2, L3, bnd, lng, lnb, pe, tokens);

    // in_proj
    k_conv<<<3 * T1, 256, 0, stream>>>(tokens, Afrag, MM, DTOK, T1);
    k_mfma<<<dim3(NT_IP, 3), 256, 0, stream>>>(Afrag, ipWf, ipb, nullptr, qkvb, T1, OQKV, 0);

    k_attn<<<160, 256, 0, stream>>>(qkvb, attnb);

    // out_proj (+tokens residual)
    k_conv<<<3 * T1, 256, 0, stream>>>(attnb, Afrag, MM, DTOK, T1);
    k_mfma<<<dim3(NT_OP, 3), 256, 0, stream>>>(Afrag, opWf, opb, tokens, x1pre, T1, DTOK, 0);

    k_ln<<<160, 256, 0, stream>>>(x1pre, n1g, n1b, x1);

    // lin1 (relu)
    k_conv<<<3 * T1, 256, 0, stream>>>(x1, Afrag, MM, DTOK, T1);
    k_mfma<<<dim3(NT_L1, 3), 256, 0, stream>>>(Afrag, l1Wf, l1b, nullptr, hb, T1, FFD, 1);

    // lin2 (+x1 residual)
    k_conv<<<3 * T2, 256, 0, stream>>>(hb, Afrag, MM, FFD, T2);
    k_mfma<<<dim3(NT_L2, 3), 256, 0, stream>>>(Afrag, l2Wf, l2b, x1, x2pre, T2, DTOK, 0);

    k_ln<<<160, 256, 0, stream>>>(x2pre, n2g, n2b, x2);
    k_fc<<<160, 256, 0, stream>>>(x2, fcw, fcb, bnd, outp + it * 320);
  }
}